// Round 21
// baseline (108.724 us; speedup 1.0000x reference)
//
#include <hip/hip_runtime.h>

#define DM   1024
#define SEQ  2048
#define NH   16
#define HD   64
#define ROWS 4096   // B*S = 2*2048

typedef unsigned short u16;
typedef unsigned int   u32;
typedef __attribute__((ext_vector_type(8))) __bf16 bf16x8;
typedef __attribute__((ext_vector_type(4))) float  f32x4;
typedef __attribute__((ext_vector_type(16))) float f32x16;

__device__ __forceinline__ u16 f2bf(float f) {
  u32 u = __builtin_bit_cast(u32, f);
  u += 0x7fffu + ((u >> 16) & 1u);   // RNE (finite values only)
  return (u16)(u >> 16);
}

__device__ __forceinline__ void async16(const void* g, void* lds) {
  __builtin_amdgcn_global_load_lds((const __attribute__((address_space(1))) u32*)g,
                                   (__attribute__((address_space(3))) u32*)lds, 16, 0, 0);
}

// ---------------- activations f32 -> bf16 (r12-proven) ----------------

__global__ __launch_bounds__(256) void k_cvt_act(const float* __restrict__ q,
                                                 const float* __restrict__ k,
                                                 const float* __restrict__ v,
                                                 u16* __restrict__ dst) {
  const float* src = blockIdx.z == 0 ? q : (blockIdx.z == 1 ? k : v);
  u16* d = dst + (size_t)blockIdx.z * ((size_t)ROWS * DM);
  size_t i = ((size_t)blockIdx.x * 256 + threadIdx.x) * 8;
  float4 a = *(const float4*)(src + i);
  float4 b = *(const float4*)(src + i + 4);
  u32 w0 = (u32)f2bf(a.x) | ((u32)f2bf(a.y) << 16);
  u32 w1 = (u32)f2bf(a.z) | ((u32)f2bf(a.w) << 16);
  u32 w2 = (u32)f2bf(b.x) | ((u32)f2bf(b.y) << 16);
  u32 w3 = (u32)f2bf(b.z) | ((u32)f2bf(b.w) << 16);
  uint4 o4; o4.x = w0; o4.y = w1; o4.z = w2; o4.w = w3;
  *(uint4*)(d + i) = o4;
}

// Wt[n][k] = W[k][n], bf16
__global__ __launch_bounds__(256) void k_cvt_wt(const float* __restrict__ Wq,
                                                const float* __restrict__ Wk,
                                                const float* __restrict__ Wv,
                                                u16* __restrict__ wt) {
  __shared__ float t[32][33];
  const float* W = blockIdx.z == 0 ? Wq : (blockIdx.z == 1 ? Wk : Wv);
  u16* D = wt + (size_t)blockIdx.z * (DM * DM);
  int bx = blockIdx.x * 32, by = blockIdx.y * 32;
  int x = threadIdx.x, y = threadIdx.y;
  for (int i = 0; i < 32; i += 8) t[y + i][x] = W[(size_t)(by + y + i) * DM + bx + x];
  __syncthreads();
  for (int i = 0; i < 32; i += 8) D[(size_t)(bx + y + i) * DM + by + x] = f2bf(t[x][y + i]);
}

// ---------------- GEMM: C = A * Wt^T (bf16 both operands; r12-proven). ---------------
// BK=32, 128x128 tile, both A and B staged via global_load_lds (pre-swizzled
// source, linear LDS dest). Q-proj gets 0.125*log2(e) folded in. XCD swizzle (T1).

__global__ __launch_bounds__(256) void k_gemm(const u16* __restrict__ Abase,
                                              const u16* __restrict__ Btbase,
                                              u16* __restrict__ Cbase) {
  __shared__ u16 As[128 * 32];
  __shared__ u16 Bs[128 * 32];
  const int z = blockIdx.z;
  const u16* A  = Abase  + (size_t)z * ((size_t)ROWS * DM);
  const u16* Bt = Btbase + (size_t)z * (DM * DM);
  u16* C        = Cbase  + (size_t)z * ((size_t)ROWS * DM);
  const float sc = (z == 0) ? 0.18033688011112043f : 1.0f;  // 1/8 * log2(e)
  int tid = threadIdx.x, w = tid >> 6, l = tid & 63;
  int fr = l & 15, fq = l >> 4;
  int bid = blockIdx.y * 8 + blockIdx.x;          // 256 per z (256 % 8 == 0)
  int nb  = (bid & 7) * 32 + (bid >> 3);          // XCD chunk remap (bijective)
  int m0 = (nb >> 3) * 128, n0 = (nb & 7) * 128;
  int wr = (w >> 1) * 64, wc = (w & 1) * 64;
  f32x4 acc[4][4];
  for (int i = 0; i < 4; ++i) for (int j = 0; j < 4; ++j) acc[i][j] = (f32x4){0.f, 0.f, 0.f, 0.f};

  for (int k0 = 0; k0 < DM; k0 += 32) {
    __syncthreads();
    for (int c = 0; c < 2; ++c) {
      int loff = (c * 4 + w) * 1024;
      int eoff = (loff >> 1) + l * 8;
      int row = eoff >> 5;
      int blk = (eoff & 31) >> 3;
      int gblk = blk ^ ((row >> 1) & 3);
      async16(A  + (size_t)(m0 + row) * DM + k0 + (gblk << 3), (char*)As + loff);
      async16(Bt + (size_t)(n0 + row) * DM + k0 + (gblk << 3), (char*)Bs + loff);
    }
    __syncthreads();
    bf16x8 af[4], bf[4];
    for (int i = 0; i < 4; ++i) {
      int row = wr + i * 16 + fr;
      af[i] = *(const bf16x8*)(As + row * 32 + ((fq ^ ((row >> 1) & 3)) << 3));
    }
    for (int j = 0; j < 4; ++j) {
      int row = wc + j * 16 + fr;
      bf[j] = *(const bf16x8*)(Bs + row * 32 + ((fq ^ ((row >> 1) & 3)) << 3));
    }
    for (int i = 0; i < 4; ++i)
      for (int j = 0; j < 4; ++j)
        acc[i][j] = __builtin_amdgcn_mfma_f32_16x16x32_bf16(af[i], bf[j], acc[i][j], 0, 0, 0);
  }
  for (int i = 0; i < 4; ++i)
    for (int j = 0; j < 4; ++j)
      for (int jj = 0; jj < 4; ++jj) {
        int row = m0 + wr + i * 16 + fq * 4 + jj;
        int col = n0 + wc + j * 16 + fr;
        C[(size_t)row * DM + col] = f2bf(acc[i][j][jj] * sc);
      }
}

// ---------------- V transpose: Vt[hb][d][s], PV-fragment-ready layout ----------------
// Per 64-key chunk, per row d: phys 16B block p holds logical block B = p ^ (d&7),
// B = 2g+half: keys 16g + {4*half+0..3, 8+4*half+0..3}. One b128 = one PV A-frag.

__global__ __launch_bounds__(256) void k_vt(const u16* __restrict__ vproj,
                                            u16* __restrict__ vt) {
  __shared__ u16 t[64][64];
  int y = blockIdx.y;            // hb = h*2 + b
  int h = y >> 1, b = y & 1;
  int s0 = blockIdx.x * 64;
  int tid = threadIdx.x;
  for (int c = 0; c < 2; ++c) {
    int rr = c * 32 + (tid >> 3);
    int blk = tid & 7;
    uint4 vv = *(const uint4*)(vproj + (size_t)(b * SEQ + s0 + rr) * DM + h * 64 + blk * 8);
    *(uint4*)(&t[rr][((blk ^ (rr & 7)) * 8)]) = vv;
  }
  __syncthreads();
  for (int c = 0; c < 2; ++c) {
    int d = c * 32 + (tid >> 3);
    int p = tid & 7;                    // phys block
    int B = p ^ (d & 7);
    int g = B >> 1, half = B & 1;
    u16 tmp[8];
    for (int j = 0; j < 8; ++j) {
      int kj = (j < 4) ? (4 * half + j) : (8 + 4 * half + (j - 4));
      int ss = 16 * g + kj;             // logical local key
      tmp[j] = t[ss][((d >> 3) ^ (ss & 7)) * 8 + (d & 7)];
    }
    *(uint4*)(vt + (size_t)(y * 64 + d) * SEQ + s0 + p * 8) = *(uint4*)tmp;
  }
}

// ---------------- attention (round-12 proven structure; bf16 output) ----------------
// grid 512 (XCD-remapped); block covers 128 q-rows. Wave w = (qg=w>>1, kh=w&1)
// computes BOTH 32-q halves of its q-group -> each K/V LDS fragment read feeds
// TWO MFMAs. Swapped QK^T, no max-subtraction, T15, counted vmcnt.

__global__ __launch_bounds__(256, 2) void k_attn(const u16* __restrict__ Qp,
                                                 const u16* __restrict__ Kp,
                                                 const u16* __restrict__ Vt,
                                                 u16* __restrict__ attb) {
  __shared__ u16 lds[20480];   // bytes [0,16K): K dbuf; [16K,40K): V tbuf
  const int tid = threadIdx.x, w = tid >> 6, l = tid & 63;
  const int lrow = l & 31, h = l >> 5;
  const int kh = w & 1, qg = w >> 1;
  const int g = blockIdx.x;
  const int vy = (g & 7) * 4 + ((g >> 3) & 3);   // same-vy blocks share an XCD
  const int vx = g >> 5;
  const int head = vy >> 1, b = vy & 1;
  const int hcol = head * 64;
  const int q0w = vx * 128 + qg * 64;            // this wave's 64 q-rows

  bf16x8 qb00, qb01, qb02, qb03, qb10, qb11, qb12, qb13;
  {
    const u16* qr0 = Qp + (size_t)(b * SEQ + q0w + lrow) * DM + hcol + h * 8;
    qb00 = *(const bf16x8*)(qr0);
    qb01 = *(const bf16x8*)(qr0 + 16);
    qb02 = *(const bf16x8*)(qr0 + 32);
    qb03 = *(const bf16x8*)(qr0 + 48);
    const u16* qr1 = Qp + (size_t)(b * SEQ + q0w + 32 + lrow) * DM + hcol + h * 8;
    qb10 = *(const bf16x8*)(qr1);
    qb11 = *(const bf16x8*)(qr1 + 16);
    qb12 = *(const bf16x8*)(qr1 + 32);
    qb13 = *(const bf16x8*)(qr1 + 48);
  }

  const int sw = lrow & 7;
  const int kbase = kh * 4096 + lrow * 128;
  const int B0 = kbase + (((0 + h) ^ sw) << 4);
  const int B1 = kbase + (((2 + h) ^ sw) << 4);
  const int B2 = kbase + (((4 + h) ^ sw) << 4);
  const int B3 = kbase + (((6 + h) ^ sw) << 4);

  const int vfb = lrow * 128;
  const int V0 = vfb + (((4 * kh + 0 + h) ^ sw) << 4);
  const int V1 = vfb + (((4 * kh + 2 + h) ^ sw) << 4);

  const int ldo0 = w * 1024, ldo1 = (4 + w) * 1024;
  const int e0 = (ldo0 >> 1) + l * 8, e1 = (ldo1 >> 1) + l * 8;
  const int r0 = e0 >> 6, r1 = e1 >> 6;
  const int kb0 = ((e0 & 63) >> 3) ^ (r0 & 7), kb1 = ((e1 & 63) >> 3) ^ (r1 & 7);
  const u32 koff0 = (u32)((b * SEQ + r0) * DM + hcol + kb0 * 8);
  const u32 koff1 = (u32)((b * SEQ + r1) * DM + hcol + kb1 * 8);
  const u32 voff0 = (u32)((vy * 64 + r0) * SEQ + (e0 & 63));
  const u32 voff1 = (u32)((vy * 64 + r1) * SEQ + (e1 & 63));

  const f32x16 kzero = {};
  f32x16 ot00 = {}, ot01 = {}, ot10 = {}, ot11 = {};  // [qpair][dhalf]
  float lacc0 = 0.f, lacc1 = 0.f;
  bf16x8 pb00 = {}, pb01 = {}, pb10 = {}, pb11 = {};  // P of tile t-1 [qpair][slice]

  char* base = (char*)lds;
  async16(Kp + koff0, base + ldo0);
  async16(Kp + koff1, base + ldo1);
  async16(Vt + voff0, base + 16384 + ldo0);
  async16(Vt + voff1, base + 16384 + ldo1);

  int vwr = 1, vcr = 0, vrd = 2;
  for (int t = 0; t < SEQ / 64; ++t) {
    {
      u32 u = (t + 1 < SEQ / 64) ? (u32)(t + 1) : (u32)(SEQ / 64 - 1);
      u32 kadv = u * (64 * DM);
      u32 vadv = u * 64;
      char* kd = base + ((t + 1) & 1) * 8192;
      char* vd = base + 16384 + vwr * 8192;
      async16(Kp + kadv + koff0, kd + ldo0);
      async16(Kp + kadv + koff1, kd + ldo1);
      async16(Vt + vadv + voff0, vd + ldo0);
      async16(Vt + vadv + voff1, vd + ldo1);
    }
    asm volatile("s_waitcnt vmcnt(6)" ::: "memory");
    __builtin_amdgcn_s_barrier();
    asm volatile("" ::: "memory");

    const char* Kb = base + (t & 1) * 8192;
    bf16x8 a0 = *(const bf16x8*)(Kb + B0);
    bf16x8 a1 = *(const bf16x8*)(Kb + B1);
    bf16x8 a2 = *(const bf16x8*)(Kb + B2);
    bf16x8 a3 = *(const bf16x8*)(Kb + B3);
    __builtin_amdgcn_s_setprio(1);
    f32x16 st0 = __builtin_amdgcn_mfma_f32_32x32x16_bf16(a0, qb00, kzero, 0, 0, 0);
    f32x16 st1 = __builtin_amdgcn_mfma_f32_32x32x16_bf16(a0, qb10, kzero, 0, 0, 0);
    st0 = __builtin_amdgcn_mfma_f32_32x32x16_bf16(a1, qb01, st0, 0, 0, 0);
    st1 = __builtin_amdgcn_mfma_f32_32x32x16_bf16(a1, qb11, st1, 0, 0, 0);
    st0 = __builtin_amdgcn_mfma_f32_32x32x16_bf16(a2, qb02, st0, 0, 0, 0);
    st1 = __builtin_amdgcn_mfma_f32_32x32x16_bf16(a2, qb12, st1, 0, 0, 0);
    st0 = __builtin_amdgcn_mfma_f32_32x32x16_bf16(a3, qb03, st0, 0, 0, 0);
    st1 = __builtin_amdgcn_mfma_f32_32x32x16_bf16(a3, qb13, st1, 0, 0, 0);
    __builtin_amdgcn_s_setprio(0);

    if (t) {
      const char* Vb = base + 16384 + vrd * 8192;
      bf16x8 vf0 = *(const bf16x8*)(Vb + V0);
      bf16x8 vf1 = *(const bf16x8*)(Vb + V1);
      bf16x8 vf2 = *(const bf16x8*)(Vb + 4096 + V0);
      bf16x8 vf3 = *(const bf16x8*)(Vb + 4096 + V1);
      __builtin_amdgcn_s_setprio(1);
      ot00 = __builtin_amdgcn_mfma_f32_32x32x16_bf16(vf0, pb00, ot00, 0, 0, 0);
      ot10 = __builtin_amdgcn_mfma_f32_32x32x16_bf16(vf0, pb10, ot10, 0, 0, 0);
      ot00 = __builtin_amdgcn_mfma_f32_32x32x16_bf16(vf1, pb01, ot00, 0, 0, 0);
      ot10 = __builtin_amdgcn_mfma_f32_32x32x16_bf16(vf1, pb11, ot10, 0, 0, 0);
      ot01 = __builtin_amdgcn_mfma_f32_32x32x16_bf16(vf2, pb00, ot01, 0, 0, 0);
      ot11 = __builtin_amdgcn_mfma_f32_32x32x16_bf16(vf2, pb10, ot11, 0, 0, 0);
      ot01 = __builtin_amdgcn_mfma_f32_32x32x16_bf16(vf3, pb01, ot01, 0, 0, 0);
      ot11 = __builtin_amdgcn_mfma_f32_32x32x16_bf16(vf3, pb11, ot11, 0, 0, 0);
      __builtin_amdgcn_s_setprio(0);
    }

    {
      f32x16 p;
#pragma unroll
      for (int i = 0; i < 16; ++i) p[i] = __builtin_amdgcn_exp2f(st0[i]);
      float s0 = (p[0] + p[1]) + (p[2] + p[3]);
      float s1 = (p[4] + p[5]) + (p[6] + p[7]);
      float s2 = (p[8] + p[9]) + (p[10] + p[11]);
      float s3 = (p[12] + p[13]) + (p[14] + p[15]);
      lacc0 += (s0 + s1) + (s2 + s3);
#pragma unroll
      for (int j = 0; j < 8; ++j) { pb00[j] = (__bf16)p[j]; pb01[j] = (__bf16)p[8 + j]; }
    }
    {
      f32x16 p;
#pragma unroll
      for (int i = 0; i < 16; ++i) p[i] = __builtin_amdgcn_exp2f(st1[i]);
      float s0 = (p[0] + p[1]) + (p[2] + p[3]);
      float s1 = (p[4] + p[5]) + (p[6] + p[7]);
      float s2 = (p[8] + p[9]) + (p[10] + p[11]);
      float s3 = (p[12] + p[13]) + (p[14] + p[15]);
      lacc1 += (s0 + s1) + (s2 + s3);
#pragma unroll
      for (int j = 0; j < 8; ++j) { pb10[j] = (__bf16)p[j]; pb11[j] = (__bf16)p[8 + j]; }
    }

    asm volatile("" ::: "memory");
    __builtin_amdgcn_s_barrier();
    asm volatile("" ::: "memory");

    int tmp = vrd; vrd = vcr; vcr = vwr; vwr = tmp;
  }

  asm volatile("s_waitcnt vmcnt(0)" ::: "memory");
  __builtin_amdgcn_s_barrier();
  asm volatile("" ::: "memory");
  {
    const char* Vb = base + 16384 + vrd * 8192;
    bf16x8 vf0 = *(const bf16x8*)(Vb + V0);
    bf16x8 vf1 = *(const bf16x8*)(Vb + V1);
    bf16x8 vf2 = *(const bf16x8*)(Vb + 4096 + V0);
    bf16x8 vf3 = *(const bf16x8*)(Vb + 4096 + V1);
    ot00 = __builtin_amdgcn_mfma_f32_32x32x16_bf16(vf0, pb00, ot00, 0, 0, 0);
    ot10 = __builtin_amdgcn_mfma_f32_32x32x16_bf16(vf0, pb10, ot10, 0, 0, 0);
    ot00 = __builtin_amdgcn_mfma_f32_32x32x16_bf16(vf1, pb01, ot00, 0, 0, 0);
    ot10 = __builtin_amdgcn_mfma_f32_32x32x16_bf16(vf1, pb11, ot10, 0, 0, 0);
    ot01 = __builtin_amdgcn_mfma_f32_32x32x16_bf16(vf2, pb00, ot01, 0, 0, 0);
    ot11 = __builtin_amdgcn_mfma_f32_32x32x16_bf16(vf2, pb10, ot11, 0, 0, 0);
    ot01 = __builtin_amdgcn_mfma_f32_32x32x16_bf16(vf3, pb01, ot01, 0, 0, 0);
    ot11 = __builtin_amdgcn_mfma_f32_32x32x16_bf16(vf3, pb11, ot11, 0, 0, 0);
  }
  lacc0 += __shfl_xor(lacc0, 32);
  lacc1 += __shfl_xor(lacc1, 32);

  // ---- merge wave pairs (same qg, kh=0/1); kh=0 writes bf16 att ----
  __syncthreads();
  float* mrg = (float*)lds;                 // 2 slots x 4352 floats = 34.8 KB
  const int slot = qg * 4352;
  if (kh) {
#pragma unroll
    for (int r = 0; r < 16; ++r) {
      mrg[slot + r * 64 + l] = ot00[r];
      mrg[slot + (16 + r) * 64 + l] = ot01[r];
      mrg[slot + (32 + r) * 64 + l] = ot10[r];
      mrg[slot + (48 + r) * 64 + l] = ot11[r];
    }
    mrg[slot + 4096 + l] = lacc0;
    mrg[slot + 4160 + l] = lacc1;
  }
  __syncthreads();
  if (!kh) {
    float inv0 = 1.f / (lacc0 + mrg[slot + 4096 + l]);
    float inv1 = 1.f / (lacc1 + mrg[slot + 4160 + l]);
    u16* orow0 = attb + (size_t)(b * SEQ + q0w + lrow) * DM + hcol + 4 * h;
    u16* orow1 = attb + (size_t)(b * SEQ + q0w + 32 + lrow) * DM + hcol + 4 * h;
#pragma unroll
    for (int G = 0; G < 4; ++G) {
      uint2 o;
      o.x = (u32)f2bf((ot00[4*G+0] + mrg[slot + (4*G+0)*64 + l]) * inv0)
          | ((u32)f2bf((ot00[4*G+1] + mrg[slot + (4*G+1)*64 + l]) * inv0) << 16);
      o.y = (u32)f2bf((ot00[4*G+2] + mrg[slot + (4*G+2)*64 + l]) * inv0)
          | ((u32)f2bf((ot00[4*G+3] + mrg[slot + (4*G+3)*64 + l]) * inv0) << 16);
      *(uint2*)(orow0 + 8 * G) = o;
      uint2 o1;
      o1.x = (u32)f2bf((ot01[4*G+0] + mrg[slot + (16+4*G+0)*64 + l]) * inv0)
           | ((u32)f2bf((ot01[4*G+1] + mrg[slot + (16+4*G+1)*64 + l]) * inv0) << 16);
      o1.y = (u32)f2bf((ot01[4*G+2] + mrg[slot + (16+4*G+2)*64 + l]) * inv0)
           | ((u32)f2bf((ot01[4*G+3] + mrg[slot + (16+4*G+3)*64 + l]) * inv0) << 16);
      *(uint2*)(orow0 + 32 + 8 * G) = o1;
      uint2 o2;
      o2.x = (u32)f2bf((ot10[4*G+0] + mrg[slot + (32+4*G+0)*64 + l]) * inv1)
           | ((u32)f2bf((ot10[4*G+1] + mrg[slot + (32+4*G+1)*64 + l]) * inv1) << 16);
      o2.y = (u32)f2bf((ot10[4*G+2] + mrg[slot + (32+4*G+2)*64 + l]) * inv1)
           | ((u32)f2bf((ot10[4*G+3] + mrg[slot + (32+4*G+3)*64 + l]) * inv1) << 16);
      *(uint2*)(orow1 + 8 * G) = o2;
      uint2 o3;
      o3.x = (u32)f2bf((ot11[4*G+0] + mrg[slot + (48+4*G+0)*64 + l]) * inv1)
           | ((u32)f2bf((ot11[4*G+1] + mrg[slot + (48+4*G+1)*64 + l]) * inv1) << 16);
      o3.y = (u32)f2bf((ot11[4*G+2] + mrg[slot + (48+4*G+2)*64 + l]) * inv1)
           | ((u32)f2bf((ot11[4*G+3] + mrg[slot + (48+4*G+3)*64 + l]) * inv1) << 16);
      *(uint2*)(orow1 + 32 + 8 * G) = o3;
    }
  }
}

// ---------------- residual + LayerNorm (att in bf16) ----------------

__global__ __launch_bounds__(256) void k_ln(const u16* __restrict__ attb,
                                            const float* __restrict__ qin,
                                            const float* __restrict__ gamma,
                                            const float* __restrict__ beta,
                                            float* __restrict__ out) {
  __shared__ float rsum[4], rsum2[4];
  int row = blockIdx.x, t = threadIdx.x;
  size_t off = (size_t)row * DM + t * 4;
  uint2 av = *(const uint2*)(attb + off);
  float4 a;
  a.x = __builtin_bit_cast(float, av.x << 16);
  a.y = __builtin_bit_cast(float, av.x & 0xffff0000u);
  a.z = __builtin_bit_cast(float, av.y << 16);
  a.w = __builtin_bit_cast(float, av.y & 0xffff0000u);
  float4 q = *(const float4*)(qin + off);
  float4 x; x.x = a.x + q.x; x.y = a.y + q.y; x.z = a.z + q.z; x.w = a.w + q.w;
  float s = x.x + x.y + x.z + x.w;
  float s2 = x.x * x.x + x.y * x.y + x.z * x.z + x.w * x.w;
  for (int o2 = 1; o2 < 64; o2 <<= 1) { s += __shfl_xor(s, o2); s2 += __shfl_xor(s2, o2); }
  int w = t >> 6, l = t & 63;
  if (l == 0) { rsum[w] = s; rsum2[w] = s2; }
  __syncthreads();
  s = rsum[0] + rsum[1] + rsum[2] + rsum[3];
  s2 = rsum2[0] + rsum2[1] + rsum2[2] + rsum2[3];
  float mean = s * (1.f / DM);
  float var = s2 * (1.f / DM) - mean * mean;
  float rstd = rsqrtf(var + 1e-8f);
  float4 g = *(const float4*)(gamma + t * 4);
  float4 be = *(const float4*)(beta + t * 4);
  float4 r;
  r.x = (x.x - mean) * rstd * g.x + be.x;
  r.y = (x.y - mean) * rstd * g.y + be.y;
  r.z = (x.z - mean) * rstd * g.z + be.z;
  r.w = (x.w - mean) * rstd * g.w + be.w;
  *(float4*)(out + off) = r;
}

// ---------------- launch ----------------

extern "C" void kernel_launch(void* const* d_in, const int* in_sizes, int n_in,
                              void* d_out, int out_size, void* d_ws, size_t ws_size,
                              hipStream_t stream) {
  (void)in_sizes; (void)n_in; (void)out_size; (void)ws_size;
  const float* q     = (const float*)d_in[0];
  const float* k     = (const float*)d_in[1];
  const float* v     = (const float*)d_in[2];
  const float* Wq    = (const float*)d_in[3];
  const float* Wk    = (const float*)d_in[4];
  const float* Wv    = (const float*)d_in[5];
  const float* gamma = (const float*)d_in[6];
  const float* beta  = (const float*)d_in[7];
  float* out = (float*)d_out;
  char* ws = (char*)d_ws;

  const size_t ACT_B = 3ull * ROWS * DM * 2;   // 24 MB bf16 activations
  const size_t WT_B  = 3ull * DM * DM * 2;     //  6 MB bf16 transposed weights

  u16* actb  = (u16*)ws;                          //  0..24 MB (dead after GEMM)
  u16* wtb   = (u16*)(ws + ACT_B);                // 24..30 MB
  u16* projb = (u16*)(ws + ACT_B + WT_B);         // 30..54 MB (q/k/v projections)
  u16* vt    = (u16*)ws;                          //  0..8  MB (aliases dead actb)
  u16* attb  = (u16*)(ws + 8ull * 1024 * 1024);   //  8..16 MB (aliases dead actb)

  k_cvt_act<<<dim3(2048, 1, 3), 256, 0, stream>>>(q, k, v, actb);
  k_cvt_wt<<<dim3(32, 32, 3), dim3(32, 8), 0, stream>>>(Wq, Wk, Wv, wtb);
  k_gemm<<<dim3(8, 32, 3), 256, 0, stream>>>(actb, wtb, projb);
  k_vt<<<dim3(SEQ / 64, NH * 2), 256, 0, stream>>>(projb + 2ull * ROWS * DM, vt);
  k_attn<<<512, 256, 0, stream>>>(projb, projb + (size_t)ROWS * DM, vt, attb);
  k_ln<<<ROWS, 256, 0, stream>>>(attb, q, gamma, beta, out);
}

// Round 22
// 102.653 us; speedup vs baseline: 1.0591x; 1.0591x over previous
//
#include <hip/hip_runtime.h>

#define DM   1024
#define SEQ  2048
#define NH   16
#define HD   64
#define ROWS 4096   // B*S = 2*2048

typedef unsigned short u16;
typedef unsigned int   u32;
typedef __attribute__((ext_vector_type(8))) __bf16 bf16x8;
typedef __attribute__((ext_vector_type(4))) float  f32x4;
typedef __attribute__((ext_vector_type(16))) float f32x16;

__device__ __forceinline__ u16 f2bf(float f) {
  u32 u = __builtin_bit_cast(u32, f);
  u += 0x7fffu + ((u >> 16) & 1u);   // RNE (finite values only)
  return (u16)(u >> 16);
}

__device__ __forceinline__ void async16(const void* g, void* lds) {
  __builtin_amdgcn_global_load_lds((const __attribute__((address_space(1))) u32*)g,
                                   (__attribute__((address_space(3))) u32*)lds, 16, 0, 0);
}

// Wt[n][k] = W[k][n], bf16
__global__ __launch_bounds__(256) void k_cvt_wt(const float* __restrict__ Wq,
                                                const float* __restrict__ Wk,
                                                const float* __restrict__ Wv,
                                                u16* __restrict__ wt) {
  __shared__ float t[32][33];
  const float* W = blockIdx.z == 0 ? Wq : (blockIdx.z == 1 ? Wk : Wv);
  u16* D = wt + (size_t)blockIdx.z * (DM * DM);
  int bx = blockIdx.x * 32, by = blockIdx.y * 32;
  int x = threadIdx.x, y = threadIdx.y;
  for (int i = 0; i < 32; i += 8) t[y + i][x] = W[(size_t)(by + y + i) * DM + bx + x];
  __syncthreads();
  for (int i = 0; i < 32; i += 8) D[(size_t)(bx + y + i) * DM + by + x] = f2bf(t[x][y + i]);
}

// ---------------- GEMM: C = A(f32, converted in-kernel) * Wt^T (bf16). --------------
// r20 base + FULL LDS DOUBLE-BUFFER: one __syncthreads per phase (was two).
// Phase t: ds_write A(t+1) (regs prefetched at t-1) -> As[nxt]; B-stage(t+1) ->
// Bs[nxt] (async16); issue A-f32(t+2); ds_read+MFMA tile t from buf[cur]; barrier.
// Q-proj gets 0.125*log2(e) folded in. XCD swizzle (T1).

__global__ __launch_bounds__(256) void k_gemm(const float* __restrict__ qf,
                                              const float* __restrict__ kf,
                                              const float* __restrict__ vf,
                                              const u16* __restrict__ Btbase,
                                              u16* __restrict__ Cbase) {
  __shared__ u16 As[2][128 * 32];   // 2 x 8 KB
  __shared__ u16 Bs[2][128 * 32];   // 2 x 8 KB
  const int z = blockIdx.z;
  const float* A = z == 0 ? qf : (z == 1 ? kf : vf);
  const u16* Bt = Btbase + (size_t)z * (DM * DM);
  u16* C        = Cbase  + (size_t)z * ((size_t)ROWS * DM);
  const float sc = (z == 0) ? 0.18033688011112043f : 1.0f;  // 1/8 * log2(e)
  int tid = threadIdx.x, w = tid >> 6, l = tid & 63;
  int fr = l & 15, fq = l >> 4;
  int bid = blockIdx.y * 8 + blockIdx.x;          // 256 per z (256 % 8 == 0)
  int nb  = (bid & 7) * 32 + (bid >> 3);          // XCD chunk remap (bijective)
  int m0 = (nb >> 3) * 128, n0 = (nb & 7) * 128;
  int wr = (w >> 1) * 64, wc = (w & 1) * 64;
  f32x4 acc[4][4];
  for (int i = 0; i < 4; ++i) for (int j = 0; j < 4; ++j) acc[i][j] = (f32x4){0.f, 0.f, 0.f, 0.f};

  // A-staging geometry: chunk c (0..511): row=c>>2, blk=c&3; thread owns c=tid, tid+256
  const int row0 = tid >> 2, blk0 = tid & 3;      // rows 0..63
  const int row1 = row0 + 64;                     // rows 64..127
  const size_t abase0 = (size_t)(m0 + row0) * DM + blk0 * 8;
  const size_t abase1 = (size_t)(m0 + row1) * DM + blk0 * 8;
  const int awr0 = row0 * 32 + ((blk0 ^ ((row0 >> 1) & 3)) << 3);  // swizzled LDS elem idx
  const int awr1 = row1 * 32 + ((blk0 ^ ((row1 >> 1) & 3)) << 3);

  float4 p0lo, p0hi, p1lo, p1hi;   // prefetched A f32 (8 elems per row-chunk)

  // ---- prologue: tile 0 fully staged into buf 0; A f32 of tile 1 in regs ----
  p0lo = *(const float4*)(A + abase0);
  p0hi = *(const float4*)(A + abase0 + 4);
  p1lo = *(const float4*)(A + abase1);
  p1hi = *(const float4*)(A + abase1 + 4);
  {
    uint4 o;
    o.x = (u32)f2bf(p0lo.x) | ((u32)f2bf(p0lo.y) << 16);
    o.y = (u32)f2bf(p0lo.z) | ((u32)f2bf(p0lo.w) << 16);
    o.z = (u32)f2bf(p0hi.x) | ((u32)f2bf(p0hi.y) << 16);
    o.w = (u32)f2bf(p0hi.z) | ((u32)f2bf(p0hi.w) << 16);
    *(uint4*)(&As[0][awr0]) = o;
    uint4 o1;
    o1.x = (u32)f2bf(p1lo.x) | ((u32)f2bf(p1lo.y) << 16);
    o1.y = (u32)f2bf(p1lo.z) | ((u32)f2bf(p1lo.w) << 16);
    o1.z = (u32)f2bf(p1hi.x) | ((u32)f2bf(p1hi.y) << 16);
    o1.w = (u32)f2bf(p1hi.z) | ((u32)f2bf(p1hi.w) << 16);
    *(uint4*)(&As[0][awr1]) = o1;
  }
  for (int c = 0; c < 2; ++c) {
    int loff = (c * 4 + w) * 1024;
    int eoff = (loff >> 1) + l * 8;
    int row = eoff >> 5;
    int blk = (eoff & 31) >> 3;
    int gblk = blk ^ ((row >> 1) & 3);
    async16(Bt + (size_t)(n0 + row) * DM + (gblk << 3), (char*)Bs[0] + loff);
  }
  p0lo = *(const float4*)(A + abase0 + 32);
  p0hi = *(const float4*)(A + abase0 + 36);
  p1lo = *(const float4*)(A + abase1 + 32);
  p1hi = *(const float4*)(A + abase1 + 36);
  __syncthreads();

  for (int k0 = 0; k0 < DM; k0 += 32) {
    const int cur = (k0 >> 5) & 1, nxt = cur ^ 1;
    if (k0 + 32 < DM) {
      // stage tile t+1: A regs -> LDS (swizzled), B via async16
      {
        uint4 o;
        o.x = (u32)f2bf(p0lo.x) | ((u32)f2bf(p0lo.y) << 16);
        o.y = (u32)f2bf(p0lo.z) | ((u32)f2bf(p0lo.w) << 16);
        o.z = (u32)f2bf(p0hi.x) | ((u32)f2bf(p0hi.y) << 16);
        o.w = (u32)f2bf(p0hi.z) | ((u32)f2bf(p0hi.w) << 16);
        *(uint4*)(&As[nxt][awr0]) = o;
        uint4 o1;
        o1.x = (u32)f2bf(p1lo.x) | ((u32)f2bf(p1lo.y) << 16);
        o1.y = (u32)f2bf(p1lo.z) | ((u32)f2bf(p1lo.w) << 16);
        o1.z = (u32)f2bf(p1hi.x) | ((u32)f2bf(p1hi.y) << 16);
        o1.w = (u32)f2bf(p1hi.z) | ((u32)f2bf(p1hi.w) << 16);
        *(uint4*)(&As[nxt][awr1]) = o1;
      }
      for (int c = 0; c < 2; ++c) {
        int loff = (c * 4 + w) * 1024;
        int eoff = (loff >> 1) + l * 8;
        int row = eoff >> 5;
        int blk = (eoff & 31) >> 3;
        int gblk = blk ^ ((row >> 1) & 3);
        async16(Bt + (size_t)(n0 + row) * DM + (k0 + 32) + (gblk << 3), (char*)Bs[nxt] + loff);
      }
      if (k0 + 64 < DM) {
        p0lo = *(const float4*)(A + abase0 + k0 + 64);
        p0hi = *(const float4*)(A + abase0 + k0 + 68);
        p1lo = *(const float4*)(A + abase1 + k0 + 64);
        p1hi = *(const float4*)(A + abase1 + k0 + 68);
      }
    }

    // compute tile t from buf[cur]
    bf16x8 af[4], bf[4];
    for (int i = 0; i < 4; ++i) {
      int row = wr + i * 16 + fr;
      af[i] = *(const bf16x8*)(&As[cur][row * 32 + ((fq ^ ((row >> 1) & 3)) << 3)]);
    }
    for (int j = 0; j < 4; ++j) {
      int row = wc + j * 16 + fr;
      bf[j] = *(const bf16x8*)(&Bs[cur][row * 32 + ((fq ^ ((row >> 1) & 3)) << 3)]);
    }
    for (int i = 0; i < 4; ++i)
      for (int j = 0; j < 4; ++j)
        acc[i][j] = __builtin_amdgcn_mfma_f32_16x16x32_bf16(af[i], bf[j], acc[i][j], 0, 0, 0);

    __syncthreads();   // single per-phase barrier: staging drained, reads done
  }
  for (int i = 0; i < 4; ++i)
    for (int j = 0; j < 4; ++j)
      for (int jj = 0; jj < 4; ++jj) {
        int row = m0 + wr + i * 16 + fq * 4 + jj;
        int col = n0 + wc + j * 16 + fr;
        C[(size_t)row * DM + col] = f2bf(acc[i][j][jj] * sc);
      }
}

// ---------------- V transpose: Vt[hb][d][s], PV-fragment-ready layout ----------------
// Per 64-key chunk, per row d: phys 16B block p holds logical block B = p ^ (d&7),
// B = 2g+half: keys 16g + {4*half+0..3, 8+4*half+0..3}. One b128 = one PV A-frag.

__global__ __launch_bounds__(256) void k_vt(const u16* __restrict__ vproj,
                                            u16* __restrict__ vt) {
  __shared__ u16 t[64][64];
  int y = blockIdx.y;            // hb = h*2 + b
  int h = y >> 1, b = y & 1;
  int s0 = blockIdx.x * 64;
  int tid = threadIdx.x;
  for (int c = 0; c < 2; ++c) {
    int rr = c * 32 + (tid >> 3);
    int blk = tid & 7;
    uint4 vv = *(const uint4*)(vproj + (size_t)(b * SEQ + s0 + rr) * DM + h * 64 + blk * 8);
    *(uint4*)(&t[rr][((blk ^ (rr & 7)) * 8)]) = vv;
  }
  __syncthreads();
  for (int c = 0; c < 2; ++c) {
    int d = c * 32 + (tid >> 3);
    int p = tid & 7;                    // phys block
    int B = p ^ (d & 7);
    int g = B >> 1, half = B & 1;
    u16 tmp[8];
    for (int j = 0; j < 8; ++j) {
      int kj = (j < 4) ? (4 * half + j) : (8 + 4 * half + (j - 4));
      int ss = 16 * g + kj;             // logical local key
      tmp[j] = t[ss][((d >> 3) ^ (ss & 7)) * 8 + (d & 7)];
    }
    *(uint4*)(vt + (size_t)(y * 64 + d) * SEQ + s0 + p * 8) = *(uint4*)tmp;
  }
}

// ---------------- attention (round-12 proven structure; bf16 output) ----------------
// grid 512 (XCD-remapped); block covers 128 q-rows. Wave w = (qg=w>>1, kh=w&1)
// computes BOTH 32-q halves of its q-group -> each K/V LDS fragment read feeds
// TWO MFMAs. Swapped QK^T, no max-subtraction, T15, counted vmcnt.

__global__ __launch_bounds__(256, 2) void k_attn(const u16* __restrict__ Qp,
                                                 const u16* __restrict__ Kp,
                                                 const u16* __restrict__ Vt,
                                                 u16* __restrict__ attb) {
  __shared__ u16 lds[20480];   // bytes [0,16K): K dbuf; [16K,40K): V tbuf
  const int tid = threadIdx.x, w = tid >> 6, l = tid & 63;
  const int lrow = l & 31, h = l >> 5;
  const int kh = w & 1, qg = w >> 1;
  const int g = blockIdx.x;
  const int vy = (g & 7) * 4 + ((g >> 3) & 3);   // same-vy blocks share an XCD
  const int vx = g >> 5;
  const int head = vy >> 1, b = vy & 1;
  const int hcol = head * 64;
  const int q0w = vx * 128 + qg * 64;            // this wave's 64 q-rows

  bf16x8 qb00, qb01, qb02, qb03, qb10, qb11, qb12, qb13;
  {
    const u16* qr0 = Qp + (size_t)(b * SEQ + q0w + lrow) * DM + hcol + h * 8;
    qb00 = *(const bf16x8*)(qr0);
    qb01 = *(const bf16x8*)(qr0 + 16);
    qb02 = *(const bf16x8*)(qr0 + 32);
    qb03 = *(const bf16x8*)(qr0 + 48);
    const u16* qr1 = Qp + (size_t)(b * SEQ + q0w + 32 + lrow) * DM + hcol + h * 8;
    qb10 = *(const bf16x8*)(qr1);
    qb11 = *(const bf16x8*)(qr1 + 16);
    qb12 = *(const bf16x8*)(qr1 + 32);
    qb13 = *(const bf16x8*)(qr1 + 48);
  }

  const int sw = lrow & 7;
  const int kbase = kh * 4096 + lrow * 128;
  const int B0 = kbase + (((0 + h) ^ sw) << 4);
  const int B1 = kbase + (((2 + h) ^ sw) << 4);
  const int B2 = kbase + (((4 + h) ^ sw) << 4);
  const int B3 = kbase + (((6 + h) ^ sw) << 4);

  const int vfb = lrow * 128;
  const int V0 = vfb + (((4 * kh + 0 + h) ^ sw) << 4);
  const int V1 = vfb + (((4 * kh + 2 + h) ^ sw) << 4);

  const int ldo0 = w * 1024, ldo1 = (4 + w) * 1024;
  const int e0 = (ldo0 >> 1) + l * 8, e1 = (ldo1 >> 1) + l * 8;
  const int r0 = e0 >> 6, r1 = e1 >> 6;
  const int kb0 = ((e0 & 63) >> 3) ^ (r0 & 7), kb1 = ((e1 & 63) >> 3) ^ (r1 & 7);
  const u32 koff0 = (u32)((b * SEQ + r0) * DM + hcol + kb0 * 8);
  const u32 koff1 = (u32)((b * SEQ + r1) * DM + hcol + kb1 * 8);
  const u32 voff0 = (u32)((vy * 64 + r0) * SEQ + (e0 & 63));
  const u32 voff1 = (u32)((vy * 64 + r1) * SEQ + (e1 & 63));

  const f32x16 kzero = {};
  f32x16 ot00 = {}, ot01 = {}, ot10 = {}, ot11 = {};  // [qpair][dhalf]
  float lacc0 = 0.f, lacc1 = 0.f;
  bf16x8 pb00 = {}, pb01 = {}, pb10 = {}, pb11 = {};  // P of tile t-1 [qpair][slice]

  char* base = (char*)lds;
  async16(Kp + koff0, base + ldo0);
  async16(Kp + koff1, base + ldo1);
  async16(Vt + voff0, base + 16384 + ldo0);
  async16(Vt + voff1, base + 16384 + ldo1);

  int vwr = 1, vcr = 0, vrd = 2;
  for (int t = 0; t < SEQ / 64; ++t) {
    {
      u32 u = (t + 1 < SEQ / 64) ? (u32)(t + 1) : (u32)(SEQ / 64 - 1);
      u32 kadv = u * (64 * DM);
      u32 vadv = u * 64;
      char* kd = base + ((t + 1) & 1) * 8192;
      char* vd = base + 16384 + vwr * 8192;
      async16(Kp + kadv + koff0, kd + ldo0);
      async16(Kp + kadv + koff1, kd + ldo1);
      async16(Vt + vadv + voff0, vd + ldo0);
      async16(Vt + vadv + voff1, vd + ldo1);
    }
    asm volatile("s_waitcnt vmcnt(6)" ::: "memory");
    __builtin_amdgcn_s_barrier();
    asm volatile("" ::: "memory");

    const char* Kb = base + (t & 1) * 8192;
    bf16x8 a0 = *(const bf16x8*)(Kb + B0);
    bf16x8 a1 = *(const bf16x8*)(Kb + B1);
    bf16x8 a2 = *(const bf16x8*)(Kb + B2);
    bf16x8 a3 = *(const bf16x8*)(Kb + B3);
    __builtin_amdgcn_s_setprio(1);
    f32x16 st0 = __builtin_amdgcn_mfma_f32_32x32x16_bf16(a0, qb00, kzero, 0, 0, 0);
    f32x16 st1 = __builtin_amdgcn_mfma_f32_32x32x16_bf16(a0, qb10, kzero, 0, 0, 0);
    st0 = __builtin_amdgcn_mfma_f32_32x32x16_bf16(a1, qb01, st0, 0, 0, 0);
    st1 = __builtin_amdgcn_mfma_f32_32x32x16_bf16(a1, qb11, st1, 0, 0, 0);
    st0 = __builtin_amdgcn_mfma_f32_32x32x16_bf16(a2, qb02, st0, 0, 0, 0);
    st1 = __builtin_amdgcn_mfma_f32_32x32x16_bf16(a2, qb12, st1, 0, 0, 0);
    st0 = __builtin_amdgcn_mfma_f32_32x32x16_bf16(a3, qb03, st0, 0, 0, 0);
    st1 = __builtin_amdgcn_mfma_f32_32x32x16_bf16(a3, qb13, st1, 0, 0, 0);
    __builtin_amdgcn_s_setprio(0);

    if (t) {
      const char* Vb = base + 16384 + vrd * 8192;
      bf16x8 vf0 = *(const bf16x8*)(Vb + V0);
      bf16x8 vf1 = *(const bf16x8*)(Vb + V1);
      bf16x8 vf2 = *(const bf16x8*)(Vb + 4096 + V0);
      bf16x8 vf3 = *(const bf16x8*)(Vb + 4096 + V1);
      __builtin_amdgcn_s_setprio(1);
      ot00 = __builtin_amdgcn_mfma_f32_32x32x16_bf16(vf0, pb00, ot00, 0, 0, 0);
      ot10 = __builtin_amdgcn_mfma_f32_32x32x16_bf16(vf0, pb10, ot10, 0, 0, 0);
      ot00 = __builtin_amdgcn_mfma_f32_32x32x16_bf16(vf1, pb01, ot00, 0, 0, 0);
      ot10 = __builtin_amdgcn_mfma_f32_32x32x16_bf16(vf1, pb11, ot10, 0, 0, 0);
      ot01 = __builtin_amdgcn_mfma_f32_32x32x16_bf16(vf2, pb00, ot01, 0, 0, 0);
      ot11 = __builtin_amdgcn_mfma_f32_32x32x16_bf16(vf2, pb10, ot11, 0, 0, 0);
      ot01 = __builtin_amdgcn_mfma_f32_32x32x16_bf16(vf3, pb01, ot01, 0, 0, 0);
      ot11 = __builtin_amdgcn_mfma_f32_32x32x16_bf16(vf3, pb11, ot11, 0, 0, 0);
      __builtin_amdgcn_s_setprio(0);
    }

    {
      f32x16 p;
#pragma unroll
      for (int i = 0; i < 16; ++i) p[i] = __builtin_amdgcn_exp2f(st0[i]);
      float s0 = (p[0] + p[1]) + (p[2] + p[3]);
      float s1 = (p[4] + p[5]) + (p[6] + p[7]);
      float s2 = (p[8] + p[9]) + (p[10] + p[11]);
      float s3 = (p[12] + p[13]) + (p[14] + p[15]);
      lacc0 += (s0 + s1) + (s2 + s3);
#pragma unroll
      for (int j = 0; j < 8; ++j) { pb00[j] = (__bf16)p[j]; pb01[j] = (__bf16)p[8 + j]; }
    }
    {
      f32x16 p;
#pragma unroll
      for (int i = 0; i < 16; ++i) p[i] = __builtin_amdgcn_exp2f(st1[i]);
      float s0 = (p[0] + p[1]) + (p[2] + p[3]);
      float s1 = (p[4] + p[5]) + (p[6] + p[7]);
      float s2 = (p[8] + p[9]) + (p[10] + p[11]);
      float s3 = (p[12] + p[13]) + (p[14] + p[15]);
      lacc1 += (s0 + s1) + (s2 + s3);
#pragma unroll
      for (int j = 0; j < 8; ++j) { pb10[j] = (__bf16)p[j]; pb11[j] = (__bf16)p[8 + j]; }
    }

    asm volatile("" ::: "memory");
    __builtin_amdgcn_s_barrier();
    asm volatile("" ::: "memory");

    int tmp = vrd; vrd = vcr; vcr = vwr; vwr = tmp;
  }

  asm volatile("s_waitcnt vmcnt(0)" ::: "memory");
  __builtin_amdgcn_s_barrier();
  asm volatile("" ::: "memory");
  {
    const char* Vb = base + 16384 + vrd * 8192;
    bf16x8 vf0 = *(const bf16x8*)(Vb + V0);
    bf16x8 vf1 = *(const bf16x8*)(Vb + V1);
    bf16x8 vf2 = *(const bf16x8*)(Vb + 4096 + V0);
    bf16x8 vf3 = *(const bf16x8*)(Vb + 4096 + V1);
    ot00 = __builtin_amdgcn_mfma_f32_32x32x16_bf16(vf0, pb00, ot00, 0, 0, 0);
    ot10 = __builtin_amdgcn_mfma_f32_32x32x16_bf16(vf0, pb10, ot10, 0, 0, 0);
    ot00 = __builtin_amdgcn_mfma_f32_32x32x16_bf16(vf1, pb01, ot00, 0, 0, 0);
    ot10 = __builtin_amdgcn_mfma_f32_32x32x16_bf16(vf1, pb11, ot10, 0, 0, 0);
    ot01 = __builtin_amdgcn_mfma_f32_32x32x16_bf16(vf2, pb00, ot01, 0, 0, 0);
    ot11 = __builtin_amdgcn_mfma_f32_32x32x16_bf16(vf2, pb10, ot11, 0, 0, 0);
    ot01 = __builtin_amdgcn_mfma_f32_32x32x16_bf16(vf3, pb01, ot01, 0, 0, 0);
    ot11 = __builtin_amdgcn_mfma_f32_32x32x16_bf16(vf3, pb11, ot11, 0, 0, 0);
  }
  lacc0 += __shfl_xor(lacc0, 32);
  lacc1 += __shfl_xor(lacc1, 32);

  // ---- merge wave pairs (same qg, kh=0/1); kh=0 writes bf16 att ----
  __syncthreads();
  float* mrg = (float*)lds;                 // 2 slots x 4352 floats = 34.8 KB
  const int slot = qg * 4352;
  if (kh) {
#pragma unroll
    for (int r = 0; r < 16; ++r) {
      mrg[slot + r * 64 + l] = ot00[r];
      mrg[slot + (16 + r) * 64 + l] = ot01[r];
      mrg[slot + (32 + r) * 64 + l] = ot10[r];
      mrg[slot + (48 + r) * 64 + l] = ot11[r];
    }
    mrg[slot + 4096 + l] = lacc0;
    mrg[slot + 4160 + l] = lacc1;
  }
  __syncthreads();
  if (!kh) {
    float inv0 = 1.f / (lacc0 + mrg[slot + 4096 + l]);
    float inv1 = 1.f / (lacc1 + mrg[slot + 4160 + l]);
    u16* orow0 = attb + (size_t)(b * SEQ + q0w + lrow) * DM + hcol + 4 * h;
    u16* orow1 = attb + (size_t)(b * SEQ + q0w + 32 + lrow) * DM + hcol + 4 * h;
#pragma unroll
    for (int G = 0; G < 4; ++G) {
      uint2 o;
      o.x = (u32)f2bf((ot00[4*G+0] + mrg[slot + (4*G+0)*64 + l]) * inv0)
          | ((u32)f2bf((ot00[4*G+1] + mrg[slot + (4*G+1)*64 + l]) * inv0) << 16);
      o.y = (u32)f2bf((ot00[4*G+2] + mrg[slot + (4*G+2)*64 + l]) * inv0)
          | ((u32)f2bf((ot00[4*G+3] + mrg[slot + (4*G+3)*64 + l]) * inv0) << 16);
      *(uint2*)(orow0 + 8 * G) = o;
      uint2 o1;
      o1.x = (u32)f2bf((ot01[4*G+0] + mrg[slot + (16+4*G+0)*64 + l]) * inv0)
           | ((u32)f2bf((ot01[4*G+1] + mrg[slot + (16+4*G+1)*64 + l]) * inv0) << 16);
      o1.y = (u32)f2bf((ot01[4*G+2] + mrg[slot + (16+4*G+2)*64 + l]) * inv0)
           | ((u32)f2bf((ot01[4*G+3] + mrg[slot + (16+4*G+3)*64 + l]) * inv0) << 16);
      *(uint2*)(orow0 + 32 + 8 * G) = o1;
      uint2 o2;
      o2.x = (u32)f2bf((ot10[4*G+0] + mrg[slot + (32+4*G+0)*64 + l]) * inv1)
           | ((u32)f2bf((ot10[4*G+1] + mrg[slot + (32+4*G+1)*64 + l]) * inv1) << 16);
      o2.y = (u32)f2bf((ot10[4*G+2] + mrg[slot + (32+4*G+2)*64 + l]) * inv1)
           | ((u32)f2bf((ot10[4*G+3] + mrg[slot + (32+4*G+3)*64 + l]) * inv1) << 16);
      *(uint2*)(orow1 + 8 * G) = o2;
      uint2 o3;
      o3.x = (u32)f2bf((ot11[4*G+0] + mrg[slot + (48+4*G+0)*64 + l]) * inv1)
           | ((u32)f2bf((ot11[4*G+1] + mrg[slot + (48+4*G+1)*64 + l]) * inv1) << 16);
      o3.y = (u32)f2bf((ot11[4*G+2] + mrg[slot + (48+4*G+2)*64 + l]) * inv1)
           | ((u32)f2bf((ot11[4*G+3] + mrg[slot + (48+4*G+3)*64 + l]) * inv1) << 16);
      *(uint2*)(orow1 + 32 + 8 * G) = o3;
    }
  }
}

// ---------------- residual + LayerNorm (att in bf16) ----------------

__global__ __launch_bounds__(256) void k_ln(const u16* __restrict__ attb,
                                            const float* __restrict__ qin,
                                            const float* __restrict__ gamma,
                                            const float* __restrict__ beta,
                                            float* __restrict__ out) {
  __shared__ float rsum[4], rsum2[4];
  int row = blockIdx.x, t = threadIdx.x;
  size_t off = (size_t)row * DM + t * 4;
  uint2 av = *(const uint2*)(attb + off);
  float4 a;
  a.x = __builtin_bit_cast(float, av.x << 16);
  a.y = __builtin_bit_cast(float, av.x & 0xffff0000u);
  a.z = __builtin_bit_cast(float, av.y << 16);
  a.w = __builtin_bit_cast(float, av.y & 0xffff0000u);
  float4 q = *(const float4*)(qin + off);
  float4 x; x.x = a.x + q.x; x.y = a.y + q.y; x.z = a.z + q.z; x.w = a.w + q.w;
  float s = x.x + x.y + x.z + x.w;
  float s2 = x.x * x.x + x.y * x.y + x.z * x.z + x.w * x.w;
  for (int o2 = 1; o2 < 64; o2 <<= 1) { s += __shfl_xor(s, o2); s2 += __shfl_xor(s2, o2); }
  int w = t >> 6, l = t & 63;
  if (l == 0) { rsum[w] = s; rsum2[w] = s2; }
  __syncthreads();
  s = rsum[0] + rsum[1] + rsum[2] + rsum[3];
  s2 = rsum2[0] + rsum2[1] + rsum2[2] + rsum2[3];
  float mean = s * (1.f / DM);
  float var = s2 * (1.f / DM) - mean * mean;
  float rstd = rsqrtf(var + 1e-8f);
  float4 g = *(const float4*)(gamma + t * 4);
  float4 be = *(const float4*)(beta + t * 4);
  float4 r;
  r.x = (x.x - mean) * rstd * g.x + be.x;
  r.y = (x.y - mean) * rstd * g.y + be.y;
  r.z = (x.z - mean) * rstd * g.z + be.z;
  r.w = (x.w - mean) * rstd * g.w + be.w;
  *(float4*)(out + off) = r;
}

// ---------------- launch ----------------

extern "C" void kernel_launch(void* const* d_in, const int* in_sizes, int n_in,
                              void* d_out, int out_size, void* d_ws, size_t ws_size,
                              hipStream_t stream) {
  (void)in_sizes; (void)n_in; (void)out_size; (void)ws_size;
  const float* q     = (const float*)d_in[0];
  const float* k     = (const float*)d_in[1];
  const float* v     = (const float*)d_in[2];
  const float* Wq    = (const float*)d_in[3];
  const float* Wk    = (const float*)d_in[4];
  const float* Wv    = (const float*)d_in[5];
  const float* gamma = (const float*)d_in[6];
  const float* beta  = (const float*)d_in[7];
  float* out = (float*)d_out;
  char* ws = (char*)d_ws;

  const size_t WT_B   = 3ull * DM * DM * 2;       //  6 MB
  const size_t PROJ_B = 3ull * ROWS * DM * 2;     // 24 MB
  const size_t VT_B   = (size_t)NH * 2 * HD * SEQ * 2;  // 8 MB

  u16* wtb   = (u16*)ws;                          //  0..6  MB
  u16* projb = (u16*)(ws + WT_B);                 //  6..30 MB
  u16* vt    = (u16*)(ws + WT_B + PROJ_B);        // 30..38 MB
  u16* attb  = (u16*)(ws + WT_B + PROJ_B + VT_B); // 38..46 MB

  k_cvt_wt<<<dim3(32, 32, 3), dim3(32, 8), 0, stream>>>(Wq, Wk, Wv, wtb);
  k_gemm<<<dim3(8, 32, 3), 256, 0, stream>>>(q, k, v, wtb, projb);
  k_vt<<<dim3(SEQ / 64, NH * 2), 256, 0, stream>>>(projb + 2ull * ROWS * DM, vt);
  k_attn<<<512, 256, 0, stream>>>(projb, projb + (size_t)ROWS * DM, vt, attb);
  k_ln<<<ROWS, 256, 0, stream>>>(attb, q, gamma, beta, out);
}